// Round 1
// baseline (562.772 us; speedup 1.0000x reference)
//
#include <hip/hip_runtime.h>
#include <math.h>

#define N_DST 50000
#define N_SRC 50000
#define NEDGE 500000
#define D 128
#define NH 8
#define HD 16

// ---------------------------------------------------------------------------
// k_prep: A1T[h][k] = (W1@W4)[k][h], A2T[h][k] = (W2@W4)[k][h], a3[h] = (W3@W4)[h]
// ---------------------------------------------------------------------------
__global__ void k_prep(const float* __restrict__ W1, const float* __restrict__ W2,
                       const float* __restrict__ W3, const float* __restrict__ W4,
                       float* __restrict__ A1T, float* __restrict__ A2T,
                       float* __restrict__ a3) {
  int t = blockIdx.x * blockDim.x + threadIdx.x;
  if (t < 2048) {
    const float* W = (t < 1024) ? W1 : W2;
    float* A = (t < 1024) ? A1T : A2T;
    int i = t & 1023;
    int k = i >> 3, h = i & 7;
    float s = 0.f;
    for (int j = 0; j < D; ++j) s += W[k * D + j] * W4[j * NH + h];
    A[h * D + k] = s;  // transposed for LDS-friendly access
  } else if (t < 2048 + NH) {
    int h = t - 2048;
    float s = 0.f;
    for (int k = 0; k < D; ++k) s += W3[k] * W4[k * NH + h];
    a3[h] = s;
  }
}

// ---------------------------------------------------------------------------
// k_rowproj: outV = feats @ W (D x D), outAttn = feats @ A (D x NH, A given
// transposed as AT[NH][D]).  W staged in LDS; one wave per row.
// ---------------------------------------------------------------------------
__global__ __launch_bounds__(256, 2) void k_rowproj(
    const float* __restrict__ feats, const float* __restrict__ W,
    const float* __restrict__ AT, float* __restrict__ outV,
    float* __restrict__ outAttn, int nrows) {
  __shared__ float sW[D * D];      // 64 KB
  __shared__ float sA[NH * D];     // 4 KB
  __shared__ float sRow[4][D];     // 2 KB
  int tid = threadIdx.x;
  {
    const float4* Wp = (const float4*)W;
    float4* sWp = (float4*)sW;
    for (int i = tid; i < D * D / 4; i += 256) sWp[i] = Wp[i];
    const float4* Ap = (const float4*)AT;
    float4* sAp = (float4*)sA;
    for (int i = tid; i < NH * D / 4; i += 256) sAp[i] = Ap[i];
  }
  __syncthreads();
  int lane = tid & 63, wid = tid >> 6;
  int wstride = gridDim.x * 4;
  const float2* sW2 = (const float2*)sW;
  const float2* sA2 = (const float2*)sA;
  for (int row = blockIdx.x * 4 + wid; row < nrows; row += wstride) {
    float2 f = ((const float2*)feats)[(size_t)row * 64 + lane];
    ((float2*)sRow[wid])[lane] = f;
    asm volatile("s_waitcnt lgkmcnt(0)" ::: "memory");
    float2 acc = {0.f, 0.f};
#pragma unroll 8
    for (int k = 0; k < D; ++k) {
      float a = sRow[wid][k];          // wave-uniform broadcast
      float2 w = sW2[k * 64 + lane];   // coalesced LDS
      acc.x += a * w.x;
      acc.y += a * w.y;
    }
    ((float2*)outV)[(size_t)row * 64 + lane] = acc;
    // attention projection: p[h] = sum_k row[k]*A[k][h]; lane holds k=2l,2l+1
    float p[NH];
#pragma unroll
    for (int h = 0; h < NH; ++h) {
      float2 a2 = sA2[h * 64 + lane];  // AT[h][2l..2l+1]
      p[h] = f.x * a2.x + f.y * a2.y;
    }
#pragma unroll
    for (int h = 0; h < NH; ++h)
      for (int off = 1; off < 64; off <<= 1) p[h] += __shfl_xor(p[h], off);
    if (lane == 0) {
      ((float4*)outAttn)[(size_t)row * 2] = make_float4(p[0], p[1], p[2], p[3]);
      ((float4*)outAttn)[(size_t)row * 2 + 1] = make_float4(p[4], p[5], p[6], p[7]);
    }
  }
}

// ---------------------------------------------------------------------------
// CSR build: histogram -> scan -> scatter
// ---------------------------------------------------------------------------
__global__ void k_hist(const int* __restrict__ dsti, int* __restrict__ deg) {
  int e = blockIdx.x * 256 + threadIdx.x;
  if (e < NEDGE) atomicAdd(&deg[dsti[e]], 1);
}

__global__ __launch_bounds__(1024) void k_scan(const int* __restrict__ deg,
                                               int* __restrict__ offs,
                                               int* __restrict__ pos) {
  __shared__ int wsum[16];
  __shared__ int sTot;
  __shared__ int sCarry;
  int tid = threadIdx.x, lane = tid & 63, wid = tid >> 6;
  if (tid == 0) sCarry = 0;
  __syncthreads();
  int finalTot = 0;
  for (int bse = 0; bse < N_DST; bse += 1024) {
    int i = bse + tid;
    int v = (i < N_DST) ? deg[i] : 0;
    int s = v;
#pragma unroll
    for (int o = 1; o < 64; o <<= 1) {
      int t = __shfl_up(s, o);
      if (lane >= o) s += t;
    }
    if (lane == 63) wsum[wid] = s;
    __syncthreads();
    if (wid == 0) {
      int x = (lane < 16) ? wsum[lane] : 0;
      int sx = x;
#pragma unroll
      for (int o = 1; o < 16; o <<= 1) {
        int t = __shfl_up(sx, o);
        if (lane >= o) sx += t;
      }
      if (lane < 16) wsum[lane] = sx - x;  // exclusive wave offsets
      if (lane == 15) sTot = sx;
    }
    __syncthreads();
    int carry = sCarry;
    int excl = carry + wsum[wid] + (s - v);
    if (i < N_DST) {
      offs[i] = excl;
      pos[i] = excl;
    }
    __syncthreads();
    if (tid == 0) {
      finalTot = carry + sTot;
      sCarry = finalTot;
    }
  }
  if (tid == 0) offs[N_DST] = finalTot;
}

__global__ void k_scatter(const int* __restrict__ srci, const int* __restrict__ dsti,
                          const float* __restrict__ P, const float* __restrict__ det,
                          int* __restrict__ pos, int* __restrict__ csr_src,
                          float* __restrict__ csr_p, float* __restrict__ csr_det) {
  int e = blockIdx.x * 256 + threadIdx.x;
  if (e >= NEDGE) return;
  int d = dsti[e];
  int p = atomicAdd(&pos[d], 1);
  csr_src[p] = srci[e];
  csr_p[p] = P[e];
  csr_det[p] = det[e];
}

// ---------------------------------------------------------------------------
// k_main: one wave per dst node. Online segment softmax + V aggregation.
// lane l accumulates output columns 2l,2l+1 (head h0 = l>>3).
// ---------------------------------------------------------------------------
__global__ __launch_bounds__(256) void k_main(
    const int* __restrict__ offs, const int* __restrict__ csr_src,
    const float* __restrict__ csr_p, const float* __restrict__ csr_det,
    const float* __restrict__ attn_dst, const float* __restrict__ attn_src,
    const float* __restrict__ a3g, const float* __restrict__ V,
    float* __restrict__ agg) {
  __shared__ float sExp[4][64 * NH];  // 8 KB, per-wave scratch
  int tid = threadIdx.x, lane = tid & 63, wid = tid >> 6;
  int node = blockIdx.x * 4 + wid;  // grid sized exactly: 12500*4 = 50000
  int start = offs[node], end = offs[node + 1];
  int h0 = lane >> 3;
  float adh[NH], a3h[NH];
  {
    float4 d0 = ((const float4*)attn_dst)[(size_t)node * 2];
    float4 d1 = ((const float4*)attn_dst)[(size_t)node * 2 + 1];
    adh[0] = d0.x; adh[1] = d0.y; adh[2] = d0.z; adh[3] = d0.w;
    adh[4] = d1.x; adh[5] = d1.y; adh[6] = d1.z; adh[7] = d1.w;
    float4 c0 = ((const float4*)a3g)[0];
    float4 c1 = ((const float4*)a3g)[1];
    a3h[0] = c0.x; a3h[1] = c0.y; a3h[2] = c0.z; a3h[3] = c0.w;
    a3h[4] = c1.x; a3h[5] = c1.y; a3h[6] = c1.z; a3h[7] = c1.w;
  }
  float mrun[NH];
#pragma unroll
  for (int h = 0; h < NH; ++h) mrun[h] = -1e30f;
  float mown = -1e30f;
  float ssum = 0.f;
  float2 acc = {0.f, 0.f};
  float* myExp = sExp[wid];
  for (int c0 = start; c0 < end; c0 += 64) {
    int n = end - c0;
    if (n > 64) n = 64;
    bool valid = lane < n;
    int src = 0;
    float Pe = 0.f, de = 0.f;
    if (valid) {
      src = csr_src[c0 + lane];
      Pe = csr_p[c0 + lane];
      de = csr_det[c0 + lane];
    }
    float lg[NH];
    if (valid) {
      float4 s0 = ((const float4*)attn_src)[(size_t)src * 2];
      float4 s1 = ((const float4*)attn_src)[(size_t)src * 2 + 1];
      float as[NH] = {s0.x, s0.y, s0.z, s0.w, s1.x, s1.y, s1.z, s1.w};
#pragma unroll
      for (int h = 0; h < NH; ++h) {
        float x = adh[h] + as[h] + Pe * a3h[h] + de;
        lg[h] = (x > 0.f) ? x : 0.2f * x;  // leaky_relu(0.2)
      }
    } else {
#pragma unroll
      for (int h = 0; h < NH; ++h) lg[h] = -1e30f;
    }
    // per-head wave max, merged with running max
    float nm[NH];
#pragma unroll
    for (int h = 0; h < NH; ++h) {
      float m = lg[h];
      for (int off = 1; off < 64; off <<= 1) m = fmaxf(m, __shfl_xor(m, off));
      nm[h] = fmaxf(mrun[h], m);
    }
    // own-head new max via static select chain (avoid scratch)
    float nmo = (h0 & 4) ? ((h0 & 2) ? ((h0 & 1) ? nm[7] : nm[6])
                                     : ((h0 & 1) ? nm[5] : nm[4]))
                         : ((h0 & 2) ? ((h0 & 1) ? nm[3] : nm[2])
                                     : ((h0 & 1) ? nm[1] : nm[0]));
    float r = __expf(mown - nmo);  // first chunk: exp(-1e30) = 0
    ssum *= r;
    acc.x *= r;
    acc.y *= r;
    mown = nmo;
#pragma unroll
    for (int h = 0; h < NH; ++h) mrun[h] = nm[h];
    // unnormalized exp -> LDS [lane][h]
    float e8[NH];
#pragma unroll
    for (int h = 0; h < NH; ++h) e8[h] = __expf(lg[h] - nm[h]);  // invalid -> 0
    float4* w4 = (float4*)&myExp[lane * NH];
    w4[0] = make_float4(e8[0], e8[1], e8[2], e8[3]);
    w4[1] = make_float4(e8[4], e8[5], e8[6], e8[7]);
    asm volatile("s_waitcnt lgkmcnt(0)" ::: "memory");
    // accumulate alpha-weighted V (unnormalized)
    for (int e = 0; e < n; ++e) {
      float w = myExp[e * NH + h0];  // broadcast within 8-lane head group
      int se = __shfl(src, e);
      float2 v = ((const float2*)V)[(size_t)se * 64 + lane];
      acc.x += w * v.x;
      acc.y += w * v.y;
      ssum += w;
    }
    asm volatile("s_waitcnt lgkmcnt(0)" ::: "memory");  // WAR vs next chunk
  }
  float inv = 1.f / (ssum + 1e-12f);
  ((float2*)agg)[(size_t)node * 64 + lane] = make_float2(acc.x * inv, acc.y * inv);
}

// ---------------------------------------------------------------------------
// k_out: out = LN(agg @ Wout + Wout_b + R + res_b) * g + b
// ---------------------------------------------------------------------------
__global__ __launch_bounds__(256, 2) void k_out(
    const float* __restrict__ agg, const float* __restrict__ R,
    const float* __restrict__ Wout, const float* __restrict__ Wout_b,
    const float* __restrict__ res_b, const float* __restrict__ ln_g,
    const float* __restrict__ ln_b, float* __restrict__ out) {
  __shared__ float sW[D * D];   // 64 KB
  __shared__ float sRow[4][D];  // 2 KB
  int tid = threadIdx.x;
  {
    const float4* Wp = (const float4*)Wout;
    float4* sWp = (float4*)sW;
    for (int i = tid; i < D * D / 4; i += 256) sWp[i] = Wp[i];
  }
  __syncthreads();
  int lane = tid & 63, wid = tid >> 6;
  int wstride = gridDim.x * 4;
  const float2* sW2 = (const float2*)sW;
  float2 wb = ((const float2*)Wout_b)[lane];
  float2 rb = ((const float2*)res_b)[lane];
  float2 g = ((const float2*)ln_g)[lane];
  float2 b = ((const float2*)ln_b)[lane];
  for (int row = blockIdx.x * 4 + wid; row < N_DST; row += wstride) {
    float2 a = ((const float2*)agg)[(size_t)row * 64 + lane];
    ((float2*)sRow[wid])[lane] = a;
    asm volatile("s_waitcnt lgkmcnt(0)" ::: "memory");
    float2 acc = ((const float2*)R)[(size_t)row * 64 + lane];
    acc.x += wb.x + rb.x;
    acc.y += wb.y + rb.y;
#pragma unroll 8
    for (int k = 0; k < D; ++k) {
      float s = sRow[wid][k];
      float2 w = sW2[k * 64 + lane];
      acc.x += s * w.x;
      acc.y += s * w.y;
    }
    // LayerNorm across the wave (2 cols/lane)
    float sum = acc.x + acc.y;
    for (int off = 1; off < 64; off <<= 1) sum += __shfl_xor(sum, off);
    float mu = sum * (1.f / D);
    float dx = acc.x - mu, dy = acc.y - mu;
    float sq = dx * dx + dy * dy;
    for (int off = 1; off < 64; off <<= 1) sq += __shfl_xor(sq, off);
    float rstd = rsqrtf(sq * (1.f / D) + 1e-5f);
    ((float2*)out)[(size_t)row * 64 + lane] =
        make_float2(dx * rstd * g.x + b.x, dy * rstd * g.y + b.y);
  }
}

// ---------------------------------------------------------------------------
extern "C" void kernel_launch(void* const* d_in, const int* in_sizes, int n_in,
                              void* d_out, int out_size, void* d_ws, size_t ws_size,
                              hipStream_t stream) {
  const float* dst_feats = (const float*)d_in[0];
  const float* src_feats = (const float*)d_in[1];
  const int* edge_index = (const int*)d_in[2];
  const float* P_edge = (const float*)d_in[3];
  const float* deter = (const float*)d_in[4];
  const float* W1 = (const float*)d_in[5];
  const float* W2 = (const float*)d_in[6];
  const float* W3 = (const float*)d_in[7];
  const float* W4 = (const float*)d_in[8];
  const float* Wv = (const float*)d_in[9];
  const float* Wout_w = (const float*)d_in[10];
  const float* Wout_b = (const float*)d_in[11];
  const float* res_w = (const float*)d_in[12];
  const float* res_b = (const float*)d_in[13];
  const float* ln_g = (const float*)d_in[14];
  const float* ln_b = (const float*)d_in[15];
  float* out = (float*)d_out;
  const int* src_idx = edge_index;
  const int* dst_idx = edge_index + NEDGE;

  float* base = (float*)d_ws;
  size_t off = 0;
  auto alloc = [&](size_t n) {
    float* p = base + off;
    off += (n + 63) & ~(size_t)63;
    return p;
  };
  float* A1T = alloc(1024);
  float* A2T = alloc(1024);
  float* a3 = alloc(8);
  float* attn_dst = alloc((size_t)N_DST * NH);
  float* attn_src = alloc((size_t)N_SRC * NH);
  float* V = alloc((size_t)N_SRC * D);
  float* R = alloc((size_t)N_DST * D);
  float* agg = alloc((size_t)N_DST * D);
  int* deg = (int*)alloc(N_DST);
  int* offs = (int*)alloc(N_DST + 1);
  int* pos = (int*)alloc(N_DST);
  int* csr_src = (int*)alloc(NEDGE);
  float* csr_p = alloc(NEDGE);
  float* csr_det = alloc(NEDGE);
  (void)ws_size; (void)in_sizes; (void)n_in; (void)out_size;

  hipMemsetAsync(deg, 0, N_DST * sizeof(int), stream);
  k_prep<<<9, 256, 0, stream>>>(W1, W2, W3, W4, A1T, A2T, a3);
  k_rowproj<<<512, 256, 0, stream>>>(src_feats, Wv, A2T, V, attn_src, N_SRC);
  k_rowproj<<<512, 256, 0, stream>>>(dst_feats, res_w, A1T, R, attn_dst, N_DST);
  k_hist<<<(NEDGE + 255) / 256, 256, 0, stream>>>(dst_idx, deg);
  k_scan<<<1, 1024, 0, stream>>>(deg, offs, pos);
  k_scatter<<<(NEDGE + 255) / 256, 256, 0, stream>>>(src_idx, dst_idx, P_edge, deter,
                                                     pos, csr_src, csr_p, csr_det);
  k_main<<<N_DST / 4, 256, 0, stream>>>(offs, csr_src, csr_p, csr_det, attn_dst,
                                        attn_src, a3, V, agg);
  k_out<<<512, 256, 0, stream>>>(agg, R, Wout_w, Wout_b, res_b, ln_g, ln_b, out);
}

// Round 3
// 400.208 us; speedup vs baseline: 1.4062x; 1.4062x over previous
//
#include <hip/hip_runtime.h>
#include <math.h>

#define N_DST 50000
#define N_SRC 50000
#define NEDGE 500000
#define D 128
#define NH 8
#define HD 16
#define BM 64  // rows per block in k_gemm
#define BK 32  // k-chunk staged in LDS

// ---------------------------------------------------------------------------
// k_prep: A1T[h][k] = (W1@W4)[k][h], A2T[h][k] = (W2@W4)[k][h], a3[h] = (W3@W4)[h]
// ---------------------------------------------------------------------------
__global__ void k_prep(const float* __restrict__ W1, const float* __restrict__ W2,
                       const float* __restrict__ W3, const float* __restrict__ W4,
                       float* __restrict__ A1T, float* __restrict__ A2T,
                       float* __restrict__ a3) {
  int t = blockIdx.x * blockDim.x + threadIdx.x;
  if (t < 2048) {
    const float* W = (t < 1024) ? W1 : W2;
    float* A = (t < 1024) ? A1T : A2T;
    int i = t & 1023;
    int k = i >> 3, h = i & 7;
    float s = 0.f;
    for (int j = 0; j < D; ++j) s += W[k * D + j] * W4[j * NH + h];
    A[h * D + k] = s;  // transposed: AT[h][k]
  } else if (t < 2048 + NH) {
    int h = t - 2048;
    float s = 0.f;
    for (int k = 0; k < D; ++k) s += W3[k] * W4[k * NH + h];
    a3[h] = s;
  }
}

// ---------------------------------------------------------------------------
// k_attn: outA[row][h] = feats[row] . AT[h]   (thread = one (row,head))
// ---------------------------------------------------------------------------
__global__ __launch_bounds__(256, 4) void k_attn(const float* __restrict__ feats,
                                                 const float* __restrict__ AT,
                                                 float* __restrict__ outA, int nrows) {
  __shared__ float sA[NH][D + 4];
  __shared__ float sRow[32][D + 4];
  int tid = threadIdx.x;
  for (int i = tid; i < NH * (D / 4); i += 256) {  // 256 float4s of AT
    int h = i >> 5, j = i & 31;
    float4 v = ((const float4*)AT)[i];
    *(float4*)&sA[h][j * 4] = v;
  }
  int rowbase = blockIdx.x * 32;
  {
    int r = tid >> 3, kc = (tid & 7) * 16;
    int row = rowbase + r;
    if (row >= nrows) row = nrows - 1;
    const float4* f4 = (const float4*)(feats + (size_t)row * D + kc);
#pragma unroll
    for (int j = 0; j < 4; ++j) *(float4*)&sRow[r][kc + j * 4] = f4[j];
  }
  __syncthreads();
  int r = tid >> 3, h = tid & 7;
  float p = 0.f;
#pragma unroll 8
  for (int i = 0; i < 32; ++i) {
    float4 a = *(const float4*)&sRow[r][i * 4];
    float4 w = *(const float4*)&sA[h][i * 4];
    p += a.x * w.x + a.y * w.y + a.z * w.z + a.w * w.w;
  }
  int row = rowbase + r;
  if (row < nrows) outA[(size_t)row * NH + h] = p;
}

// ---------------------------------------------------------------------------
// k_gemm: out = feats @ W  (M x 128 x 128), register-tiled.
// Block: 64 rows. Wave: 16 rows. Lane: 4 cols x 8 rows (half-wave row split).
// ---------------------------------------------------------------------------
#define FMA4(A, S) \
  A.x += w.x * (S); A.y += w.y * (S); A.z += w.z * (S); A.w += w.w * (S);

__global__ __launch_bounds__(256, 3) void k_gemm(const float* __restrict__ feats,
                                                 const float* __restrict__ W,
                                                 float* __restrict__ outp, int nrows) {
  __shared__ float sW[BK * D];       // 16 KB
  __shared__ float sRT[D][BM + 4];   // 34 KB, k-major transposed rows
  int tid = threadIdx.x;
  int rowbase = blockIdx.x * BM;
  {
    int r = tid & 63, k0 = (tid >> 6) * 32;
    int row = rowbase + r;
    if (row >= nrows) row = nrows - 1;
    const float4* f4 = (const float4*)(feats + (size_t)row * D + k0);
#pragma unroll
    for (int j = 0; j < 8; ++j) {
      float4 v = f4[j];
      int k = k0 + j * 4;
      sRT[k + 0][r] = v.x;
      sRT[k + 1][r] = v.y;
      sRT[k + 2][r] = v.z;
      sRT[k + 3][r] = v.w;
    }
  }
  int lane = tid & 63, wid = tid >> 6;
  int rw = wid * 16;
  int half = lane >> 5;
  int cl = lane & 31;
  float4 acc[8];
#pragma unroll
  for (int i = 0; i < 8; ++i) acc[i] = make_float4(0.f, 0.f, 0.f, 0.f);
  const float4* sW4 = (const float4*)sW;
  for (int kc = 0; kc < D / BK; ++kc) {
    __syncthreads();
    {
      const float4* w4 = (const float4*)(W + kc * BK * D);
      float4* s4 = (float4*)sW;
#pragma unroll
      for (int j = 0; j < 4; ++j) s4[tid + j * 256] = w4[tid + j * 256];
    }
    __syncthreads();
#pragma unroll 4
    for (int kk = 0; kk < BK; ++kk) {
      float4 w = sW4[kk * 32 + cl];
      const float* bp = &sRT[kc * BK + kk][rw + half * 8];
      float4 ba = *(const float4*)bp;
      float4 bb = *(const float4*)(bp + 4);
      FMA4(acc[0], ba.x); FMA4(acc[1], ba.y); FMA4(acc[2], ba.z); FMA4(acc[3], ba.w);
      FMA4(acc[4], bb.x); FMA4(acc[5], bb.y); FMA4(acc[6], bb.z); FMA4(acc[7], bb.w);
    }
  }
#pragma unroll
  for (int i = 0; i < 8; ++i) {
    int row = rowbase + rw + half * 8 + i;
    if (row < nrows) ((float4*)(outp + (size_t)row * D))[cl] = acc[i];
  }
}

// ---------------------------------------------------------------------------
// k_out_fused: out = LN(agg @ Wout + Wout_b + R + res_b) * g + b
// Same GEMM structure as k_gemm with fused epilogue.
// ---------------------------------------------------------------------------
__global__ __launch_bounds__(256, 3) void k_out_fused(
    const float* __restrict__ agg, const float* __restrict__ Wout,
    const float* __restrict__ R, const float* __restrict__ Wout_b,
    const float* __restrict__ res_b, const float* __restrict__ ln_g,
    const float* __restrict__ ln_b, float* __restrict__ out, int nrows) {
  __shared__ float sW[BK * D];
  __shared__ float sRT[D][BM + 4];
  int tid = threadIdx.x;
  int rowbase = blockIdx.x * BM;
  {
    int r = tid & 63, k0 = (tid >> 6) * 32;
    int row = rowbase + r;
    if (row >= nrows) row = nrows - 1;
    const float4* f4 = (const float4*)(agg + (size_t)row * D + k0);
#pragma unroll
    for (int j = 0; j < 8; ++j) {
      float4 v = f4[j];
      int k = k0 + j * 4;
      sRT[k + 0][r] = v.x;
      sRT[k + 1][r] = v.y;
      sRT[k + 2][r] = v.z;
      sRT[k + 3][r] = v.w;
    }
  }
  int lane = tid & 63, wid = tid >> 6;
  int rw = wid * 16;
  int half = lane >> 5;
  int cl = lane & 31;
  float4 acc[8];
#pragma unroll
  for (int i = 0; i < 8; ++i) acc[i] = make_float4(0.f, 0.f, 0.f, 0.f);
  const float4* sW4 = (const float4*)sW;
  for (int kc = 0; kc < D / BK; ++kc) {
    __syncthreads();
    {
      const float4* w4 = (const float4*)(Wout + kc * BK * D);
      float4* s4 = (float4*)sW;
#pragma unroll
      for (int j = 0; j < 4; ++j) s4[tid + j * 256] = w4[tid + j * 256];
    }
    __syncthreads();
#pragma unroll 4
    for (int kk = 0; kk < BK; ++kk) {
      float4 w = sW4[kk * 32 + cl];
      const float* bp = &sRT[kc * BK + kk][rw + half * 8];
      float4 ba = *(const float4*)bp;
      float4 bb = *(const float4*)(bp + 4);
      FMA4(acc[0], ba.x); FMA4(acc[1], ba.y); FMA4(acc[2], ba.z); FMA4(acc[3], ba.w);
      FMA4(acc[4], bb.x); FMA4(acc[5], bb.y); FMA4(acc[6], bb.z); FMA4(acc[7], bb.w);
    }
  }
  float4 wb = ((const float4*)Wout_b)[cl];
  float4 rb = ((const float4*)res_b)[cl];
  float4 g4 = ((const float4*)ln_g)[cl];
  float4 b4 = ((const float4*)ln_b)[cl];
#pragma unroll
  for (int i = 0; i < 8; ++i) {
    int row = rowbase + rw + half * 8 + i;
    int rc = (row < nrows) ? row : (nrows - 1);
    float4 rr = ((const float4*)(R + (size_t)rc * D))[cl];
    float4 y;
    y.x = acc[i].x + wb.x + rb.x + rr.x;
    y.y = acc[i].y + wb.y + rb.y + rr.y;
    y.z = acc[i].z + wb.z + rb.z + rr.z;
    y.w = acc[i].w + wb.w + rb.w + rr.w;
    float s = y.x + y.y + y.z + y.w;
#pragma unroll
    for (int off = 1; off < 32; off <<= 1) s += __shfl_xor(s, off);
    float mu = s * (1.f / D);
    float4 dx;
    dx.x = y.x - mu; dx.y = y.y - mu; dx.z = y.z - mu; dx.w = y.w - mu;
    float sq = dx.x * dx.x + dx.y * dx.y + dx.z * dx.z + dx.w * dx.w;
#pragma unroll
    for (int off = 1; off < 32; off <<= 1) sq += __shfl_xor(sq, off);
    float rstd = rsqrtf(sq * (1.f / D) + 1e-5f);
    float4 o;
    o.x = dx.x * rstd * g4.x + b4.x;
    o.y = dx.y * rstd * g4.y + b4.y;
    o.z = dx.z * rstd * g4.z + b4.z;
    o.w = dx.w * rstd * g4.w + b4.w;
    if (row < nrows) ((float4*)(out + (size_t)row * D))[cl] = o;
  }
}

// ---------------------------------------------------------------------------
// CSR build: histogram -> scan -> scatter
// ---------------------------------------------------------------------------
__global__ void k_hist(const int* __restrict__ dsti, int* __restrict__ deg) {
  int e = blockIdx.x * 256 + threadIdx.x;
  if (e < NEDGE) atomicAdd(&deg[dsti[e]], 1);
}

__global__ __launch_bounds__(1024) void k_scan(const int* __restrict__ deg,
                                               int* __restrict__ offs,
                                               int* __restrict__ pos) {
  __shared__ int wsum[16];
  __shared__ int sTot;
  __shared__ int sCarry;
  int tid = threadIdx.x, lane = tid & 63, wid = tid >> 6;
  if (tid == 0) sCarry = 0;
  __syncthreads();
  int finalTot = 0;
  for (int bse = 0; bse < N_DST; bse += 1024) {
    int i = bse + tid;
    int v = (i < N_DST) ? deg[i] : 0;
    int s = v;
#pragma unroll
    for (int o = 1; o < 64; o <<= 1) {
      int t = __shfl_up(s, o);
      if (lane >= o) s += t;
    }
    if (lane == 63) wsum[wid] = s;
    __syncthreads();
    if (wid == 0) {
      int x = (lane < 16) ? wsum[lane] : 0;
      int sx = x;
#pragma unroll
      for (int o = 1; o < 16; o <<= 1) {
        int t = __shfl_up(sx, o);
        if (lane >= o) sx += t;
      }
      if (lane < 16) wsum[lane] = sx - x;
      if (lane == 15) sTot = sx;
    }
    __syncthreads();
    int carry = sCarry;
    int excl = carry + wsum[wid] + (s - v);
    if (i < N_DST) {
      offs[i] = excl;
      pos[i] = excl;
    }
    __syncthreads();
    if (tid == 0) {
      finalTot = carry + sTot;
      sCarry = finalTot;
    }
  }
  if (tid == 0) offs[N_DST] = finalTot;
}

__global__ void k_scatter(const int* __restrict__ srci, const int* __restrict__ dsti,
                          const float* __restrict__ P, const float* __restrict__ det,
                          int* __restrict__ pos, int* __restrict__ csr_src,
                          float* __restrict__ csr_p, float* __restrict__ csr_det) {
  int e = blockIdx.x * 256 + threadIdx.x;
  if (e >= NEDGE) return;
  int d = dsti[e];
  int p = atomicAdd(&pos[d], 1);
  csr_src[p] = srci[e];
  csr_p[p] = P[e];
  csr_det[p] = det[e];
}

// ---------------------------------------------------------------------------
// k_main: one wave per dst node. Online segment softmax + V aggregation.
// ---------------------------------------------------------------------------
__global__ __launch_bounds__(256) void k_main(
    const int* __restrict__ offs, const int* __restrict__ csr_src,
    const float* __restrict__ csr_p, const float* __restrict__ csr_det,
    const float* __restrict__ attn_dst, const float* __restrict__ attn_src,
    const float* __restrict__ a3g, const float* __restrict__ V,
    float* __restrict__ agg) {
  __shared__ float sExp[4][64 * NH];
  int tid = threadIdx.x, lane = tid & 63, wid = tid >> 6;
  int node = blockIdx.x * 4 + wid;
  int start = offs[node], end = offs[node + 1];
  int h0 = lane >> 3;
  float adh[NH], a3h[NH];
  {
    float4 d0 = ((const float4*)attn_dst)[(size_t)node * 2];
    float4 d1 = ((const float4*)attn_dst)[(size_t)node * 2 + 1];
    adh[0] = d0.x; adh[1] = d0.y; adh[2] = d0.z; adh[3] = d0.w;
    adh[4] = d1.x; adh[5] = d1.y; adh[6] = d1.z; adh[7] = d1.w;
    float4 c0 = ((const float4*)a3g)[0];
    float4 c1 = ((const float4*)a3g)[1];
    a3h[0] = c0.x; a3h[1] = c0.y; a3h[2] = c0.z; a3h[3] = c0.w;
    a3h[4] = c1.x; a3h[5] = c1.y; a3h[6] = c1.z; a3h[7] = c1.w;
  }
  float mrun[NH];
#pragma unroll
  for (int h = 0; h < NH; ++h) mrun[h] = -1e30f;
  float mown = -1e30f;
  float ssum = 0.f;
  float2 acc = {0.f, 0.f};
  float* myExp = sExp[wid];
  for (int c0 = start; c0 < end; c0 += 64) {
    int n = end - c0;
    if (n > 64) n = 64;
    bool valid = lane < n;
    int src = 0;
    float Pe = 0.f, de = 0.f;
    if (valid) {
      src = csr_src[c0 + lane];
      Pe = csr_p[c0 + lane];
      de = csr_det[c0 + lane];
    }
    float lg[NH];
    if (valid) {
      float4 s0 = ((const float4*)attn_src)[(size_t)src * 2];
      float4 s1 = ((const float4*)attn_src)[(size_t)src * 2 + 1];
      float as[NH] = {s0.x, s0.y, s0.z, s0.w, s1.x, s1.y, s1.z, s1.w};
#pragma unroll
      for (int h = 0; h < NH; ++h) {
        float x = adh[h] + as[h] + Pe * a3h[h] + de;
        lg[h] = (x > 0.f) ? x : 0.2f * x;
      }
    } else {
#pragma unroll
      for (int h = 0; h < NH; ++h) lg[h] = -1e30f;
    }
    float nm[NH];
#pragma unroll
    for (int h = 0; h < NH; ++h) {
      float m = lg[h];
      for (int off = 1; off < 64; off <<= 1) m = fmaxf(m, __shfl_xor(m, off));
      nm[h] = fmaxf(mrun[h], m);
    }
    float nmo = (h0 & 4) ? ((h0 & 2) ? ((h0 & 1) ? nm[7] : nm[6])
                                     : ((h0 & 1) ? nm[5] : nm[4]))
                         : ((h0 & 2) ? ((h0 & 1) ? nm[3] : nm[2])
                                     : ((h0 & 1) ? nm[1] : nm[0]));
    float r = __expf(mown - nmo);
    ssum *= r;
    acc.x *= r;
    acc.y *= r;
    mown = nmo;
#pragma unroll
    for (int h = 0; h < NH; ++h) mrun[h] = nm[h];
    float e8[NH];
#pragma unroll
    for (int h = 0; h < NH; ++h) e8[h] = __expf(lg[h] - nm[h]);
    float4* w4 = (float4*)&myExp[lane * NH];
    w4[0] = make_float4(e8[0], e8[1], e8[2], e8[3]);
    w4[1] = make_float4(e8[4], e8[5], e8[6], e8[7]);
    asm volatile("s_waitcnt lgkmcnt(0)" ::: "memory");
    for (int e = 0; e < n; ++e) {
      float w = myExp[e * NH + h0];
      int se = __shfl(src, e);
      float2 v = ((const float2*)V)[(size_t)se * 64 + lane];
      acc.x += w * v.x;
      acc.y += w * v.y;
      ssum += w;
    }
    asm volatile("s_waitcnt lgkmcnt(0)" ::: "memory");
  }
  float inv = 1.f / (ssum + 1e-12f);
  ((float2*)agg)[(size_t)node * 64 + lane] = make_float2(acc.x * inv, acc.y * inv);
}

// ---------------------------------------------------------------------------
extern "C" void kernel_launch(void* const* d_in, const int* in_sizes, int n_in,
                              void* d_out, int out_size, void* d_ws, size_t ws_size,
                              hipStream_t stream) {
  const float* dst_feats = (const float*)d_in[0];
  const float* src_feats = (const float*)d_in[1];
  const int* edge_index = (const int*)d_in[2];
  const float* P_edge = (const float*)d_in[3];
  const float* deter = (const float*)d_in[4];
  const float* W1 = (const float*)d_in[5];
  const float* W2 = (const float*)d_in[6];
  const float* W3 = (const float*)d_in[7];
  const float* W4 = (const float*)d_in[8];
  const float* Wv = (const float*)d_in[9];
  const float* Wout_w = (const float*)d_in[10];
  const float* Wout_b = (const float*)d_in[11];
  const float* res_w = (const float*)d_in[12];
  const float* res_b = (const float*)d_in[13];
  const float* ln_g = (const float*)d_in[14];
  const float* ln_b = (const float*)d_in[15];
  float* out = (float*)d_out;
  const int* src_idx = edge_index;
  const int* dst_idx = edge_index + NEDGE;

  float* base = (float*)d_ws;
  size_t off = 0;
  auto alloc = [&](size_t n) {
    float* p = base + off;
    off += (n + 63) & ~(size_t)63;
    return p;
  };
  float* A1T = alloc(1024);
  float* A2T = alloc(1024);
  float* a3 = alloc(8);
  float* attn_dst = alloc((size_t)N_DST * NH);
  float* attn_src = alloc((size_t)N_SRC * NH);
  float* V = alloc((size_t)N_SRC * D);
  float* R = alloc((size_t)N_DST * D);
  float* agg = alloc((size_t)N_DST * D);
  int* deg = (int*)alloc(N_DST);
  int* offs = (int*)alloc(N_DST + 1);
  int* pos = (int*)alloc(N_DST);
  int* csr_src = (int*)alloc(NEDGE);
  float* csr_p = alloc(NEDGE);
  float* csr_det = alloc(NEDGE);
  (void)ws_size; (void)in_sizes; (void)n_in; (void)out_size;

  hipMemsetAsync(deg, 0, N_DST * sizeof(int), stream);
  k_prep<<<9, 256, 0, stream>>>(W1, W2, W3, W4, A1T, A2T, a3);
  k_attn<<<(N_SRC + 31) / 32, 256, 0, stream>>>(src_feats, A2T, attn_src, N_SRC);
  k_attn<<<(N_DST + 31) / 32, 256, 0, stream>>>(dst_feats, A1T, attn_dst, N_DST);
  k_gemm<<<(N_SRC + BM - 1) / BM, 256, 0, stream>>>(src_feats, Wv, V, N_SRC);
  k_gemm<<<(N_DST + BM - 1) / BM, 256, 0, stream>>>(dst_feats, res_w, R, N_DST);
  k_hist<<<(NEDGE + 255) / 256, 256, 0, stream>>>(dst_idx, deg);
  k_scan<<<1, 1024, 0, stream>>>(deg, offs, pos);
  k_scatter<<<(NEDGE + 255) / 256, 256, 0, stream>>>(src_idx, dst_idx, P_edge, deter,
                                                     pos, csr_src, csr_p, csr_det);
  k_main<<<N_DST / 4, 256, 0, stream>>>(offs, csr_src, csr_p, csr_det, attn_dst,
                                        attn_src, a3, V, agg);
  k_out_fused<<<(N_DST + BM - 1) / BM, 256, 0, stream>>>(
      agg, Wout_w, R, Wout_b, res_b, ln_g, ln_b, out, N_DST);
}

// Round 7
// 350.207 us; speedup vs baseline: 1.6070x; 1.1428x over previous
//
#include <hip/hip_runtime.h>
#include <math.h>

#define N_DST 50000
#define N_SRC 50000
#define NEDGE 500000
#define D 128
#define NH 8
#define HD 16
#define BM 64  // rows per block in k_gemm
#define BK 32  // k-chunk staged in LDS

// ---------------------------------------------------------------------------
// k_prep: A1T[h][k] = (W1@W4)[k][h] (block 0) / W2 (block 1); a3[h]=(W3@W4)[h]
// ---------------------------------------------------------------------------
__global__ __launch_bounds__(256) void k_prep(const float* __restrict__ W1,
                                              const float* __restrict__ W2,
                                              const float* __restrict__ W3,
                                              const float* __restrict__ W4,
                                              float* __restrict__ A1T,
                                              float* __restrict__ A2T,
                                              float* __restrict__ a3) {
  __shared__ float sW4[D * NH];  // [j][h] as stored
  int tid = threadIdx.x;
  for (int i = tid; i < D * NH / 4; i += 256)
    ((float4*)sW4)[i] = ((const float4*)W4)[i];
  __syncthreads();
  const float* W = blockIdx.x ? W2 : W1;
  float* A = blockIdx.x ? A2T : A1T;
  if (tid < D) {
    int k = tid;
    float acc[NH];
#pragma unroll
    for (int h = 0; h < NH; ++h) acc[h] = 0.f;
    for (int j = 0; j < D; j += 4) {
      float4 w = *(const float4*)(W + (size_t)k * D + j);
#pragma unroll
      for (int h = 0; h < NH; ++h) {
        acc[h] += w.x * sW4[(j + 0) * NH + h] + w.y * sW4[(j + 1) * NH + h] +
                  w.z * sW4[(j + 2) * NH + h] + w.w * sW4[(j + 3) * NH + h];
      }
    }
#pragma unroll
    for (int h = 0; h < NH; ++h) A[h * D + k] = acc[h];
  } else if (blockIdx.x == 0 && tid >= 128 && tid < 128 + NH) {
    int h = tid - 128;
    float s = 0.f;
    for (int k = 0; k < D; ++k) s += W3[k] * sW4[k * NH + h];
    a3[h] = s;
  }
}

// ---------------------------------------------------------------------------
// k_attn: outA[row][h] = feats[row] . AT[h]
// ---------------------------------------------------------------------------
__global__ __launch_bounds__(256, 4) void k_attn(const float* __restrict__ feats,
                                                 const float* __restrict__ AT,
                                                 float* __restrict__ outA, int nrows) {
  __shared__ float sA[NH][D + 4];
  __shared__ float sRow[32][D + 4];
  int tid = threadIdx.x;
  for (int i = tid; i < NH * (D / 4); i += 256) {
    int h = i >> 5, j = i & 31;
    float4 v = ((const float4*)AT)[i];
    *(float4*)&sA[h][j * 4] = v;
  }
  int rowbase = blockIdx.x * 32;
  {
    int r = tid >> 3, kc = (tid & 7) * 16;
    int row = rowbase + r;
    if (row >= nrows) row = nrows - 1;
    const float4* f4 = (const float4*)(feats + (size_t)row * D + kc);
#pragma unroll
    for (int j = 0; j < 4; ++j) *(float4*)&sRow[r][kc + j * 4] = f4[j];
  }
  __syncthreads();
  int r = tid >> 3, h = tid & 7;
  float p = 0.f;
#pragma unroll 8
  for (int i = 0; i < 32; ++i) {
    float4 a = *(const float4*)&sRow[r][i * 4];
    float4 w = *(const float4*)&sA[h][i * 4];
    p += a.x * w.x + a.y * w.y + a.z * w.z + a.w * w.w;
  }
  int row = rowbase + r;
  if (row < nrows) outA[(size_t)row * NH + h] = p;
}

// ---------------------------------------------------------------------------
// k_gemm: out = feats @ W  (M x 128 x 128), register-tiled.
// ---------------------------------------------------------------------------
#define FMA4(A, S) \
  A.x += w.x * (S); A.y += w.y * (S); A.z += w.z * (S); A.w += w.w * (S);

__global__ __launch_bounds__(256, 3) void k_gemm(const float* __restrict__ feats,
                                                 const float* __restrict__ W,
                                                 float* __restrict__ outp, int nrows) {
  __shared__ float sW[BK * D];
  __shared__ float sRT[D][BM + 4];
  int tid = threadIdx.x;
  int rowbase = blockIdx.x * BM;
  {
    int r = tid & 63, k0 = (tid >> 6) * 32;
    int row = rowbase + r;
    if (row >= nrows) row = nrows - 1;
    const float4* f4 = (const float4*)(feats + (size_t)row * D + k0);
#pragma unroll
    for (int j = 0; j < 8; ++j) {
      float4 v = f4[j];
      int k = k0 + j * 4;
      sRT[k + 0][r] = v.x;
      sRT[k + 1][r] = v.y;
      sRT[k + 2][r] = v.z;
      sRT[k + 3][r] = v.w;
    }
  }
  int lane = tid & 63, wid = tid >> 6;
  int rw = wid * 16;
  int half = lane >> 5;
  int cl = lane & 31;
  float4 acc[8];
#pragma unroll
  for (int i = 0; i < 8; ++i) acc[i] = make_float4(0.f, 0.f, 0.f, 0.f);
  const float4* sW4 = (const float4*)sW;
  for (int kc = 0; kc < D / BK; ++kc) {
    __syncthreads();
    {
      const float4* w4 = (const float4*)(W + kc * BK * D);
      float4* s4 = (float4*)sW;
#pragma unroll
      for (int j = 0; j < 4; ++j) s4[tid + j * 256] = w4[tid + j * 256];
    }
    __syncthreads();
#pragma unroll 4
    for (int kk = 0; kk < BK; ++kk) {
      float4 w = sW4[kk * 32 + cl];
      const float* bp = &sRT[kc * BK + kk][rw + half * 8];
      float4 ba = *(const float4*)bp;
      float4 bb = *(const float4*)(bp + 4);
      FMA4(acc[0], ba.x); FMA4(acc[1], ba.y); FMA4(acc[2], ba.z); FMA4(acc[3], ba.w);
      FMA4(acc[4], bb.x); FMA4(acc[5], bb.y); FMA4(acc[6], bb.z); FMA4(acc[7], bb.w);
    }
  }
#pragma unroll
  for (int i = 0; i < 8; ++i) {
    int row = rowbase + rw + half * 8 + i;
    if (row < nrows) ((float4*)(outp + (size_t)row * D))[cl] = acc[i];
  }
}

// ---------------------------------------------------------------------------
// k_out_fused: out = LN(agg @ Wout + Wout_b + R + res_b) * g + b
// ---------------------------------------------------------------------------
__global__ __launch_bounds__(256, 3) void k_out_fused(
    const float* __restrict__ agg, const float* __restrict__ Wout,
    const float* __restrict__ R, const float* __restrict__ Wout_b,
    const float* __restrict__ res_b, const float* __restrict__ ln_g,
    const float* __restrict__ ln_b, float* __restrict__ out, int nrows) {
  __shared__ float sW[BK * D];
  __shared__ float sRT[D][BM + 4];
  int tid = threadIdx.x;
  int rowbase = blockIdx.x * BM;
  {
    int r = tid & 63, k0 = (tid >> 6) * 32;
    int row = rowbase + r;
    if (row >= nrows) row = nrows - 1;
    const float4* f4 = (const float4*)(agg + (size_t)row * D + k0);
#pragma unroll
    for (int j = 0; j < 8; ++j) {
      float4 v = f4[j];
      int k = k0 + j * 4;
      sRT[k + 0][r] = v.x;
      sRT[k + 1][r] = v.y;
      sRT[k + 2][r] = v.z;
      sRT[k + 3][r] = v.w;
    }
  }
  int lane = tid & 63, wid = tid >> 6;
  int rw = wid * 16;
  int half = lane >> 5;
  int cl = lane & 31;
  float4 acc[8];
#pragma unroll
  for (int i = 0; i < 8; ++i) acc[i] = make_float4(0.f, 0.f, 0.f, 0.f);
  const float4* sW4 = (const float4*)sW;
  for (int kc = 0; kc < D / BK; ++kc) {
    __syncthreads();
    {
      const float4* w4 = (const float4*)(Wout + kc * BK * D);
      float4* s4 = (float4*)sW;
#pragma unroll
      for (int j = 0; j < 4; ++j) s4[tid + j * 256] = w4[tid + j * 256];
    }
    __syncthreads();
#pragma unroll 4
    for (int kk = 0; kk < BK; ++kk) {
      float4 w = sW4[kk * 32 + cl];
      const float* bp = &sRT[kc * BK + kk][rw + half * 8];
      float4 ba = *(const float4*)bp;
      float4 bb = *(const float4*)(bp + 4);
      FMA4(acc[0], ba.x); FMA4(acc[1], ba.y); FMA4(acc[2], ba.z); FMA4(acc[3], ba.w);
      FMA4(acc[4], bb.x); FMA4(acc[5], bb.y); FMA4(acc[6], bb.z); FMA4(acc[7], bb.w);
    }
  }
  float4 wb = ((const float4*)Wout_b)[cl];
  float4 rb = ((const float4*)res_b)[cl];
  float4 g4 = ((const float4*)ln_g)[cl];
  float4 b4 = ((const float4*)ln_b)[cl];
#pragma unroll
  for (int i = 0; i < 8; ++i) {
    int row = rowbase + rw + half * 8 + i;
    int rc = (row < nrows) ? row : (nrows - 1);
    float4 rr = ((const float4*)(R + (size_t)rc * D))[cl];
    float4 y;
    y.x = acc[i].x + wb.x + rb.x + rr.x;
    y.y = acc[i].y + wb.y + rb.y + rr.y;
    y.z = acc[i].z + wb.z + rb.z + rr.z;
    y.w = acc[i].w + wb.w + rb.w + rr.w;
    float s = y.x + y.y + y.z + y.w;
#pragma unroll
    for (int off = 1; off < 32; off <<= 1) s += __shfl_xor(s, off);
    float mu = s * (1.f / D);
    float4 dx;
    dx.x = y.x - mu; dx.y = y.y - mu; dx.z = y.z - mu; dx.w = y.w - mu;
    float sq = dx.x * dx.x + dx.y * dx.y + dx.z * dx.z + dx.w * dx.w;
#pragma unroll
    for (int off = 1; off < 32; off <<= 1) sq += __shfl_xor(sq, off);
    float rstd = rsqrtf(sq * (1.f / D) + 1e-5f);
    float4 o;
    o.x = dx.x * rstd * g4.x + b4.x;
    o.y = dx.y * rstd * g4.y + b4.y;
    o.z = dx.z * rstd * g4.z + b4.z;
    o.w = dx.w * rstd * g4.w + b4.w;
    if (row < nrows) ((float4*)(out + (size_t)row * D))[cl] = o;
  }
}

// ---------------------------------------------------------------------------
// CSR build: histogram -> 3-kernel multiblock scan -> scatter(+partial logits)
// ---------------------------------------------------------------------------
__global__ void k_hist(const int* __restrict__ dsti, int* __restrict__ deg) {
  int e = blockIdx.x * 256 + threadIdx.x;
  if (e < NEDGE) atomicAdd(&deg[dsti[e]], 1);
}

// block = 256 threads, 1024 elems: per-block total
__global__ __launch_bounds__(256) void k_scan1(const int* __restrict__ deg,
                                               int* __restrict__ bsum) {
  __shared__ int ws[4];
  int tid = threadIdx.x, lane = tid & 63, wid = tid >> 6;
  int base = blockIdx.x * 1024 + tid * 4;
  int s = 0;
#pragma unroll
  for (int i = 0; i < 4; ++i) {
    int idx = base + i;
    if (idx < N_DST) s += deg[idx];
  }
#pragma unroll
  for (int o = 1; o < 64; o <<= 1) s += __shfl_xor(s, o);
  if (lane == 0) ws[wid] = s;
  __syncthreads();
  if (tid == 0) bsum[blockIdx.x] = ws[0] + ws[1] + ws[2] + ws[3];
}

// single wave: exclusive-scan nb (<=64) block sums in place; write total
__global__ __launch_bounds__(64) void k_scan2(int* __restrict__ bsum,
                                              int* __restrict__ total, int nb) {
  int lane = threadIdx.x;
  int v = (lane < nb) ? bsum[lane] : 0;
  int s = v;
#pragma unroll
  for (int o = 1; o < 64; o <<= 1) {
    int t = __shfl_up(s, o);
    if (lane >= o) s += t;
  }
  if (lane < nb) bsum[lane] = s - v;
  if (lane == 63) total[0] = s;
}

__global__ __launch_bounds__(256) void k_scan3(const int* __restrict__ deg,
                                               const int* __restrict__ bsum,
                                               int* __restrict__ offs,
                                               int* __restrict__ pos) {
  __shared__ int ws[4];
  int tid = threadIdx.x, lane = tid & 63, wid = tid >> 6;
  int base = blockIdx.x * 1024 + tid * 4;
  int v0 = (base + 0 < N_DST) ? deg[base + 0] : 0;
  int v1 = (base + 1 < N_DST) ? deg[base + 1] : 0;
  int v2 = (base + 2 < N_DST) ? deg[base + 2] : 0;
  int v3 = (base + 3 < N_DST) ? deg[base + 3] : 0;
  int ts = v0 + v1 + v2 + v3;
  int s = ts;
#pragma unroll
  for (int o = 1; o < 64; o <<= 1) {
    int t = __shfl_up(s, o);
    if (lane >= o) s += t;
  }
  if (lane == 63) ws[wid] = s;
  __syncthreads();
  int woff = 0;
  for (int i = 0; i < wid; ++i) woff += ws[i];
  int tb = bsum[blockIdx.x] + woff + (s - ts);
  if (base + 0 < N_DST) { offs[base + 0] = tb; pos[base + 0] = tb; }
  tb += v0;
  if (base + 1 < N_DST) { offs[base + 1] = tb; pos[base + 1] = tb; }
  tb += v1;
  if (base + 2 < N_DST) { offs[base + 2] = tb; pos[base + 2] = tb; }
  tb += v2;
  if (base + 3 < N_DST) { offs[base + 3] = tb; pos[base + 3] = tb; }
}

// scatter: place edge into CSR slot; precompute partial logits (no dst term):
// pl[h] = attn_src[src][h] + P*a3[h] + det
__global__ void k_scatter(const int* __restrict__ srci, const int* __restrict__ dsti,
                          const float* __restrict__ P, const float* __restrict__ det,
                          const float* __restrict__ attn_src,
                          const float* __restrict__ a3g, int* __restrict__ pos,
                          int* __restrict__ csr_src, float* __restrict__ csr_pl) {
  int e = blockIdx.x * 256 + threadIdx.x;
  if (e >= NEDGE) return;
  int d = dsti[e];
  int sidx = srci[e];
  float pe = P[e], de = det[e];
  int p = atomicAdd(&pos[d], 1);
  csr_src[p] = sidx;
  float4 s0 = ((const float4*)attn_src)[(size_t)sidx * 2];
  float4 s1 = ((const float4*)attn_src)[(size_t)sidx * 2 + 1];
  float4 c0 = ((const float4*)a3g)[0];
  float4 c1 = ((const float4*)a3g)[1];
  float4 o0, o1;
  o0.x = s0.x + pe * c0.x + de; o0.y = s0.y + pe * c0.y + de;
  o0.z = s0.z + pe * c0.z + de; o0.w = s0.w + pe * c0.w + de;
  o1.x = s1.x + pe * c1.x + de; o1.y = s1.y + pe * c1.y + de;
  o1.z = s1.z + pe * c1.z + de; o1.w = s1.w + pe * c1.w + de;
  ((float4*)csr_pl)[(size_t)p * 2] = o0;
  ((float4*)csr_pl)[(size_t)p * 2 + 1] = o1;
}

// ---------------------------------------------------------------------------
// k_main: 8 lanes per dst node, one lane per head. All softmax state in
// registers (scalar per lane). Two passes: max, then exp+accumulate.
// Lane h owns output cols h*16..h*16+15 (4 float4 accumulators).
// ---------------------------------------------------------------------------
__global__ __launch_bounds__(256) void k_main(
    const int* __restrict__ offs, const int* __restrict__ csr_src,
    const float* __restrict__ csr_pl, const float* __restrict__ attn_dst,
    const float* __restrict__ V, float* __restrict__ agg) {
  int tid = threadIdx.x;
  int g = tid >> 3;   // node group within block (0..31)
  int h = tid & 7;    // head
  int node = blockIdx.x * 32 + g;
  if (node >= N_DST) return;
  int start = offs[node], end = offs[node + 1];
  float ad = attn_dst[(size_t)node * NH + h];

  float m = -1e30f;
#pragma unroll 2
  for (int e = start; e < end; ++e) {
    float x = ad + csr_pl[(size_t)e * NH + h];
    x = (x > 0.f) ? x : 0.2f * x;
    m = fmaxf(m, x);
  }

  float4 a0 = make_float4(0.f, 0.f, 0.f, 0.f);
  float4 a1 = a0, a2 = a0, a3v = a0;
  float ssum = 0.f;
#pragma unroll 2
  for (int e = start; e < end; ++e) {
    float x = ad + csr_pl[(size_t)e * NH + h];
    x = (x > 0.f) ? x : 0.2f * x;
    float w = __expf(x - m);
    ssum += w;
    int sidx = csr_src[e];  // broadcast within 8-lane group
    const float4* v4 = (const float4*)(V + (size_t)sidx * D + h * HD);
    float4 b0 = v4[0], b1 = v4[1], b2 = v4[2], b3 = v4[3];
    a0.x += w * b0.x; a0.y += w * b0.y; a0.z += w * b0.z; a0.w += w * b0.w;
    a1.x += w * b1.x; a1.y += w * b1.y; a1.z += w * b1.z; a1.w += w * b1.w;
    a2.x += w * b2.x; a2.y += w * b2.y; a2.z += w * b2.z; a2.w += w * b2.w;
    a3v.x += w * b3.x; a3v.y += w * b3.y; a3v.z += w * b3.z; a3v.w += w * b3.w;
  }
  float inv = 1.f / (ssum + 1e-12f);
  float4* o = (float4*)(agg + (size_t)node * D + h * HD);
  a0.x *= inv; a0.y *= inv; a0.z *= inv; a0.w *= inv;
  a1.x *= inv; a1.y *= inv; a1.z *= inv; a1.w *= inv;
  a2.x *= inv; a2.y *= inv; a2.z *= inv; a2.w *= inv;
  a3v.x *= inv; a3v.y *= inv; a3v.z *= inv; a3v.w *= inv;
  o[0] = a0; o[1] = a1; o[2] = a2; o[3] = a3v;
}

// ---------------------------------------------------------------------------
extern "C" void kernel_launch(void* const* d_in, const int* in_sizes, int n_in,
                              void* d_out, int out_size, void* d_ws, size_t ws_size,
                              hipStream_t stream) {
  const float* dst_feats = (const float*)d_in[0];
  const float* src_feats = (const float*)d_in[1];
  const int* edge_index = (const int*)d_in[2];
  const float* P_edge = (const float*)d_in[3];
  const float* deter = (const float*)d_in[4];
  const float* W1 = (const float*)d_in[5];
  const float* W2 = (const float*)d_in[6];
  const float* W3 = (const float*)d_in[7];
  const float* W4 = (const float*)d_in[8];
  const float* Wv = (const float*)d_in[9];
  const float* Wout_w = (const float*)d_in[10];
  const float* Wout_b = (const float*)d_in[11];
  const float* res_w = (const float*)d_in[12];
  const float* res_b = (const float*)d_in[13];
  const float* ln_g = (const float*)d_in[14];
  const float* ln_b = (const float*)d_in[15];
  float* out = (float*)d_out;
  const int* src_idx = edge_index;
  const int* dst_idx = edge_index + NEDGE;

  float* base = (float*)d_ws;
  size_t off = 0;
  auto alloc = [&](size_t n) {
    float* p = base + off;
    off += (n + 63) & ~(size_t)63;
    return p;
  };
  float* A1T = alloc(1024);
  float* A2T = alloc(1024);
  float* a3 = alloc(8);
  float* attn_dst = alloc((size_t)N_DST * NH);
  float* attn_src = alloc((size_t)N_SRC * NH);
  float* V = alloc((size_t)N_SRC * D);
  float* R = alloc((size_t)N_DST * D);
  float* agg = alloc((size_t)N_DST * D);
  int* deg = (int*)alloc(N_DST);
  int* offs = (int*)alloc(N_DST + 1);
  int* pos = (int*)alloc(N_DST);
  int* bsum = (int*)alloc(64);
  int* csr_src = (int*)alloc(NEDGE);
  float* csr_pl = alloc((size_t)NEDGE * NH);
  (void)ws_size; (void)in_sizes; (void)n_in; (void)out_size;

  const int NSB = (N_DST + 1023) / 1024;  // 49 scan blocks

  hipMemsetAsync(deg, 0, N_DST * sizeof(int), stream);
  k_prep<<<2, 256, 0, stream>>>(W1, W2, W3, W4, A1T, A2T, a3);
  k_attn<<<(N_SRC + 31) / 32, 256, 0, stream>>>(src_feats, A2T, attn_src, N_SRC);
  k_attn<<<(N_DST + 31) / 32, 256, 0, stream>>>(dst_feats, A1T, attn_dst, N_DST);
  k_gemm<<<(N_SRC + BM - 1) / BM, 256, 0, stream>>>(src_feats, Wv, V, N_SRC);
  k_gemm<<<(N_DST + BM - 1) / BM, 256, 0, stream>>>(dst_feats, res_w, R, N_DST);
  k_hist<<<(NEDGE + 255) / 256, 256, 0, stream>>>(dst_idx, deg);
  k_scan1<<<NSB, 256, 0, stream>>>(deg, bsum);
  k_scan2<<<1, 64, 0, stream>>>(bsum, offs + N_DST, NSB);
  k_scan3<<<NSB, 256, 0, stream>>>(deg, bsum, offs, pos);
  k_scatter<<<(NEDGE + 255) / 256, 256, 0, stream>>>(
      src_idx, dst_idx, P_edge, deter, attn_src, a3, pos, csr_src, csr_pl);
  k_main<<<(N_DST + 31) / 32, 256, 0, stream>>>(offs, csr_src, csr_pl, attn_dst, V,
                                                agg);
  k_out_fused<<<(N_DST + BM - 1) / BM, 256, 0, stream>>>(
      agg, Wout_w, R, Wout_b, res_b, ln_g, ln_b, out, N_DST);
}

// Round 10
// 331.508 us; speedup vs baseline: 1.6976x; 1.0564x over previous
//
#include <hip/hip_runtime.h>
#include <math.h>

#define N_DST 50000
#define N_SRC 50000
#define NEDGE 500000
#define D 128
#define NH 8
#define HD 16
#define BM 64  // rows per block in k_gemm
#define BK 32  // k-chunk staged in LDS

// ---------------------------------------------------------------------------
// k_prep: A1T[h][k] = (W1@W4)[k][h] (block 0) / W2 (block 1); a3[h]=(W3@W4)[h]
// ---------------------------------------------------------------------------
__global__ __launch_bounds__(256) void k_prep(const float* __restrict__ W1,
                                              const float* __restrict__ W2,
                                              const float* __restrict__ W3,
                                              const float* __restrict__ W4,
                                              float* __restrict__ A1T,
                                              float* __restrict__ A2T,
                                              float* __restrict__ a3) {
  __shared__ float sW4[D * NH];  // [j][h] as stored
  int tid = threadIdx.x;
  for (int i = tid; i < D * NH / 4; i += 256)
    ((float4*)sW4)[i] = ((const float4*)W4)[i];
  __syncthreads();
  const float* W = blockIdx.x ? W2 : W1;
  float* A = blockIdx.x ? A2T : A1T;
  if (tid < D) {
    int k = tid;
    float acc[NH];
#pragma unroll
    for (int h = 0; h < NH; ++h) acc[h] = 0.f;
    for (int j = 0; j < D; j += 4) {
      float4 w = *(const float4*)(W + (size_t)k * D + j);
#pragma unroll
      for (int h = 0; h < NH; ++h) {
        acc[h] += w.x * sW4[(j + 0) * NH + h] + w.y * sW4[(j + 1) * NH + h] +
                  w.z * sW4[(j + 2) * NH + h] + w.w * sW4[(j + 3) * NH + h];
      }
    }
#pragma unroll
    for (int h = 0; h < NH; ++h) A[h * D + k] = acc[h];
  } else if (blockIdx.x == 0 && tid >= 128 && tid < 128 + NH) {
    int h = tid - 128;
    float s = 0.f;
    for (int k = 0; k < D; ++k) s += W3[k] * sW4[k * NH + h];
    a3[h] = s;
  }
}

// ---------------------------------------------------------------------------
// k_gemm_fused: one launch does BOTH row-GEMMs (+ fused attention projection).
//   blocks [0, nblk)      : outV_A = featsA @ WA ; outAttn_A = featsA @ ATA^T
//   blocks [nblk, 2*nblk) : same with B set.
// GEMM: 64 rows/block, register-tiled (16 rows/wave, 4 cols x 8 rows / lane).
// Attn tail reuses sRT (k-major rows) + sW buffer (holds AT, 4 KB).
// ---------------------------------------------------------------------------
#define FMA4(A, S) \
  A.x += w.x * (S); A.y += w.y * (S); A.z += w.z * (S); A.w += w.w * (S);

__global__ __launch_bounds__(256, 3) void k_gemm_fused(
    const float* __restrict__ featsA, const float* __restrict__ featsB,
    const float* __restrict__ WA, const float* __restrict__ WB,
    const float* __restrict__ ATA, const float* __restrict__ ATB,
    float* __restrict__ outVA, float* __restrict__ outVB,
    float* __restrict__ outAttnA, float* __restrict__ outAttnB, int nrows,
    int nblk) {
  __shared__ float sW[BK * D];       // 16 KB (reused for AT in attn tail)
  __shared__ float sRT[D][BM + 4];   // 34.8 KB, k-major transposed rows
  int tid = threadIdx.x;
  bool first = (int)blockIdx.x < nblk;
  const float* feats = first ? featsA : featsB;
  const float* W = first ? WA : WB;
  const float* AT = first ? ATA : ATB;
  float* outV = first ? outVA : outVB;
  float* outAttn = first ? outAttnA : outAttnB;
  int rowbase = (first ? blockIdx.x : blockIdx.x - nblk) * BM;
  {
    int r = tid & 63, k0 = (tid >> 6) * 32;
    int row = rowbase + r;
    if (row >= nrows) row = nrows - 1;
    const float4* f4 = (const float4*)(feats + (size_t)row * D + k0);
#pragma unroll
    for (int j = 0; j < 8; ++j) {
      float4 v = f4[j];
      int k = k0 + j * 4;
      sRT[k + 0][r] = v.x;
      sRT[k + 1][r] = v.y;
      sRT[k + 2][r] = v.z;
      sRT[k + 3][r] = v.w;
    }
  }
  int lane = tid & 63, wid = tid >> 6;
  int rw = wid * 16;
  int half = lane >> 5;
  int cl = lane & 31;
  float4 acc[8];
#pragma unroll
  for (int i = 0; i < 8; ++i) acc[i] = make_float4(0.f, 0.f, 0.f, 0.f);
  const float4* sW4 = (const float4*)sW;
  for (int kc = 0; kc < D / BK; ++kc) {
    __syncthreads();
    {
      const float4* w4 = (const float4*)(W + kc * BK * D);
      float4* s4 = (float4*)sW;
#pragma unroll
      for (int j = 0; j < 4; ++j) s4[tid + j * 256] = w4[tid + j * 256];
    }
    __syncthreads();
#pragma unroll 4
    for (int kk = 0; kk < BK; ++kk) {
      float4 w = sW4[kk * 32 + cl];
      const float* bp = &sRT[kc * BK + kk][rw + half * 8];
      float4 ba = *(const float4*)bp;
      float4 bb = *(const float4*)(bp + 4);
      FMA4(acc[0], ba.x); FMA4(acc[1], ba.y); FMA4(acc[2], ba.z); FMA4(acc[3], ba.w);
      FMA4(acc[4], bb.x); FMA4(acc[5], bb.y); FMA4(acc[6], bb.z); FMA4(acc[7], bb.w);
    }
  }
#pragma unroll
  for (int i = 0; i < 8; ++i) {
    int row = rowbase + rw + half * 8 + i;
    if (row < nrows) ((float4*)(outV + (size_t)row * D))[cl] = acc[i];
  }
  // ---- fused attention projection: outAttn[row][h] = row . AT[h] ----
  __syncthreads();  // everyone done reading sW from last kc
  ((float4*)sW)[tid] = ((const float4*)AT)[tid];  // 1024 floats = AT[8][128]
  __syncthreads();
  {
    int r = tid & 63;      // row within block (lane)
    int hp = tid >> 6;     // head pair 0..3 (wave-uniform)
    int h0 = hp * 2, h1 = h0 + 1;
    float p0 = 0.f, p1 = 0.f;
#pragma unroll 8
    for (int k = 0; k < D; ++k) {
      float v = sRT[k][r];
      p0 += v * sW[h0 * D + k];
      p1 += v * sW[h1 * D + k];
    }
    int row = rowbase + r;
    if (row < nrows) {
      outAttn[(size_t)row * NH + h0] = p0;
      outAttn[(size_t)row * NH + h1] = p1;
    }
  }
}

// ---------------------------------------------------------------------------
// k_out_fused: out = LN(agg @ Wout + Wout_b + R + res_b) * g + b
// ---------------------------------------------------------------------------
__global__ __launch_bounds__(256, 3) void k_out_fused(
    const float* __restrict__ agg, const float* __restrict__ Wout,
    const float* __restrict__ R, const float* __restrict__ Wout_b,
    const float* __restrict__ res_b, const float* __restrict__ ln_g,
    const float* __restrict__ ln_b, float* __restrict__ out, int nrows) {
  __shared__ float sW[BK * D];
  __shared__ float sRT[D][BM + 4];
  int tid = threadIdx.x;
  int rowbase = blockIdx.x * BM;
  {
    int r = tid & 63, k0 = (tid >> 6) * 32;
    int row = rowbase + r;
    if (row >= nrows) row = nrows - 1;
    const float4* f4 = (const float4*)(agg + (size_t)row * D + k0);
#pragma unroll
    for (int j = 0; j < 8; ++j) {
      float4 v = f4[j];
      int k = k0 + j * 4;
      sRT[k + 0][r] = v.x;
      sRT[k + 1][r] = v.y;
      sRT[k + 2][r] = v.z;
      sRT[k + 3][r] = v.w;
    }
  }
  int lane = tid & 63, wid = tid >> 6;
  int rw = wid * 16;
  int half = lane >> 5;
  int cl = lane & 31;
  float4 acc[8];
#pragma unroll
  for (int i = 0; i < 8; ++i) acc[i] = make_float4(0.f, 0.f, 0.f, 0.f);
  const float4* sW4 = (const float4*)sW;
  for (int kc = 0; kc < D / BK; ++kc) {
    __syncthreads();
    {
      const float4* w4 = (const float4*)(Wout + kc * BK * D);
      float4* s4 = (float4*)sW;
#pragma unroll
      for (int j = 0; j < 4; ++j) s4[tid + j * 256] = w4[tid + j * 256];
    }
    __syncthreads();
#pragma unroll 4
    for (int kk = 0; kk < BK; ++kk) {
      float4 w = sW4[kk * 32 + cl];
      const float* bp = &sRT[kc * BK + kk][rw + half * 8];
      float4 ba = *(const float4*)bp;
      float4 bb = *(const float4*)(bp + 4);
      FMA4(acc[0], ba.x); FMA4(acc[1], ba.y); FMA4(acc[2], ba.z); FMA4(acc[3], ba.w);
      FMA4(acc[4], bb.x); FMA4(acc[5], bb.y); FMA4(acc[6], bb.z); FMA4(acc[7], bb.w);
    }
  }
  float4 wb = ((const float4*)Wout_b)[cl];
  float4 rb = ((const float4*)res_b)[cl];
  float4 g4 = ((const float4*)ln_g)[cl];
  float4 b4 = ((const float4*)ln_b)[cl];
#pragma unroll
  for (int i = 0; i < 8; ++i) {
    int row = rowbase + rw + half * 8 + i;
    int rc = (row < nrows) ? row : (nrows - 1);
    float4 rr = ((const float4*)(R + (size_t)rc * D))[cl];
    float4 y;
    y.x = acc[i].x + wb.x + rb.x + rr.x;
    y.y = acc[i].y + wb.y + rb.y + rr.y;
    y.z = acc[i].z + wb.z + rb.z + rr.z;
    y.w = acc[i].w + wb.w + rb.w + rr.w;
    float s = y.x + y.y + y.z + y.w;
#pragma unroll
    for (int off = 1; off < 32; off <<= 1) s += __shfl_xor(s, off);
    float mu = s * (1.f / D);
    float4 dx;
    dx.x = y.x - mu; dx.y = y.y - mu; dx.z = y.z - mu; dx.w = y.w - mu;
    float sq = dx.x * dx.x + dx.y * dx.y + dx.z * dx.z + dx.w * dx.w;
#pragma unroll
    for (int off = 1; off < 32; off <<= 1) sq += __shfl_xor(sq, off);
    float rstd = rsqrtf(sq * (1.f / D) + 1e-5f);
    float4 o;
    o.x = dx.x * rstd * g4.x + b4.x;
    o.y = dx.y * rstd * g4.y + b4.y;
    o.z = dx.z * rstd * g4.z + b4.z;
    o.w = dx.w * rstd * g4.w + b4.w;
    if (row < nrows) ((float4*)(out + (size_t)row * D))[cl] = o;
  }
}

// ---------------------------------------------------------------------------
// CSR build: histogram -> 3-kernel multiblock scan -> scatter (packed record)
// ---------------------------------------------------------------------------
__global__ void k_hist(const int* __restrict__ dsti, int* __restrict__ deg) {
  int e = blockIdx.x * 256 + threadIdx.x;
  if (e < NEDGE) atomicAdd(&deg[dsti[e]], 1);
}

__global__ __launch_bounds__(256) void k_scan1(const int* __restrict__ deg,
                                               int* __restrict__ bsum) {
  __shared__ int ws[4];
  int tid = threadIdx.x, lane = tid & 63, wid = tid >> 6;
  int base = blockIdx.x * 1024 + tid * 4;
  int s = 0;
#pragma unroll
  for (int i = 0; i < 4; ++i) {
    int idx = base + i;
    if (idx < N_DST) s += deg[idx];
  }
#pragma unroll
  for (int o = 1; o < 64; o <<= 1) s += __shfl_xor(s, o);
  if (lane == 0) ws[wid] = s;
  __syncthreads();
  if (tid == 0) bsum[blockIdx.x] = ws[0] + ws[1] + ws[2] + ws[3];
}

__global__ __launch_bounds__(64) void k_scan2(int* __restrict__ bsum,
                                              int* __restrict__ total, int nb) {
  int lane = threadIdx.x;
  int v = (lane < nb) ? bsum[lane] : 0;
  int s = v;
#pragma unroll
  for (int o = 1; o < 64; o <<= 1) {
    int t = __shfl_up(s, o);
    if (lane >= o) s += t;
  }
  if (lane < nb) bsum[lane] = s - v;
  if (lane == 63) total[0] = s;
}

__global__ __launch_bounds__(256) void k_scan3(const int* __restrict__ deg,
                                               const int* __restrict__ bsum,
                                               int* __restrict__ offs,
                                               int* __restrict__ pos) {
  __shared__ int ws[4];
  int tid = threadIdx.x, lane = tid & 63, wid = tid >> 6;
  int base = blockIdx.x * 1024 + tid * 4;
  int v0 = (base + 0 < N_DST) ? deg[base + 0] : 0;
  int v1 = (base + 1 < N_DST) ? deg[base + 1] : 0;
  int v2 = (base + 2 < N_DST) ? deg[base + 2] : 0;
  int v3 = (base + 3 < N_DST) ? deg[base + 3] : 0;
  int ts = v0 + v1 + v2 + v3;
  int s = ts;
#pragma unroll
  for (int o = 1; o < 64; o <<= 1) {
    int t = __shfl_up(s, o);
    if (lane >= o) s += t;
  }
  if (lane == 63) ws[wid] = s;
  __syncthreads();
  int woff = 0;
  for (int i = 0; i < wid; ++i) woff += ws[i];
  int tb = bsum[blockIdx.x] + woff + (s - ts);
  if (base + 0 < N_DST) { offs[base + 0] = tb; pos[base + 0] = tb; }
  tb += v0;
  if (base + 1 < N_DST) { offs[base + 1] = tb; pos[base + 1] = tb; }
  tb += v1;
  if (base + 2 < N_DST) { offs[base + 2] = tb; pos[base + 2] = tb; }
  tb += v2;
  if (base + 3 < N_DST) { offs[base + 3] = tb; pos[base + 3] = tb; }
}

// scatter: one packed 16B record per edge: (src_bits, P, det, 0)
__global__ void k_scatter(const int* __restrict__ srci, const int* __restrict__ dsti,
                          const float* __restrict__ P, const float* __restrict__ det,
                          int* __restrict__ pos, float4* __restrict__ csr_pk) {
  int e = blockIdx.x * 256 + threadIdx.x;
  if (e >= NEDGE) return;
  int d = dsti[e];
  int sidx = srci[e];
  float pe = P[e], de = det[e];
  int p = atomicAdd(&pos[d], 1);
  csr_pk[p] = make_float4(__int_as_float(sidx), pe, de, 0.f);
}

// ---------------------------------------------------------------------------
// k_main: 8 lanes per dst node, one lane per head. SINGLE pass, direct exp
// (no max subtraction: logits ~N(0,4), |x|<=~11 << 88 overflow bound, so
// exp(x) is safe and identical to the max-shifted softmax after division).
// Lane h owns output cols h*16..h*16+15.
// ---------------------------------------------------------------------------
__global__ __launch_bounds__(256) void k_main(
    const int* __restrict__ offs, const float4* __restrict__ csr_pk,
    const float* __restrict__ attn_src, const float* __restrict__ attn_dst,
    const float* __restrict__ a3g, const float* __restrict__ V,
    float* __restrict__ agg) {
  int tid = threadIdx.x;
  int g = tid >> 3;   // node group within block (0..31)
  int h = tid & 7;    // head
  int node = blockIdx.x * 32 + g;
  if (node >= N_DST) return;
  int start = offs[node], end = offs[node + 1];
  float ad = attn_dst[(size_t)node * NH + h];
  float a3h = a3g[h];

  float4 a0 = make_float4(0.f, 0.f, 0.f, 0.f);
  float4 a1 = a0, a2 = a0, a3v = a0;
  float ssum = 0.f;
#pragma unroll 2
  for (int e = start; e < end; ++e) {
    float4 pk = csr_pk[e];  // broadcast within 8-lane group
    int sidx = __float_as_int(pk.x);
    float x = ad + attn_src[(size_t)sidx * NH + h] + pk.y * a3h + pk.z;
    x = (x > 0.f) ? x : 0.2f * x;  // leaky_relu(0.2)
    float w = __expf(x);
    ssum += w;
    const float4* v4 = (const float4*)(V + (size_t)sidx * D + h * HD);
    float4 b0 = v4[0], b1 = v4[1], b2 = v4[2], b3 = v4[3];
    a0.x += w * b0.x; a0.y += w * b0.y; a0.z += w * b0.z; a0.w += w * b0.w;
    a1.x += w * b1.x; a1.y += w * b1.y; a1.z += w * b1.z; a1.w += w * b1.w;
    a2.x += w * b2.x; a2.y += w * b2.y; a2.z += w * b2.z; a2.w += w * b2.w;
    a3v.x += w * b3.x; a3v.y += w * b3.y; a3v.z += w * b3.z; a3v.w += w * b3.w;
  }
  float inv = 1.f / (ssum + 1e-12f);
  float4* o = (float4*)(agg + (size_t)node * D + h * HD);
  a0.x *= inv; a0.y *= inv; a0.z *= inv; a0.w *= inv;
  a1.x *= inv; a1.y *= inv; a1.z *= inv; a1.w *= inv;
  a2.x *= inv; a2.y *= inv; a2.z *= inv; a2.w *= inv;
  a3v.x *= inv; a3v.y *= inv; a3v.z *= inv; a3v.w *= inv;
  o[0] = a0; o[1] = a1; o[2] = a2; o[3] = a3v;
}

// ---------------------------------------------------------------------------
extern "C" void kernel_launch(void* const* d_in, const int* in_sizes, int n_in,
                              void* d_out, int out_size, void* d_ws, size_t ws_size,
                              hipStream_t stream) {
  const float* dst_feats = (const float*)d_in[0];
  const float* src_feats = (const float*)d_in[1];
  const int* edge_index = (const int*)d_in[2];
  const float* P_edge = (const float*)d_in[3];
  const float* deter = (const float*)d_in[4];
  const float* W1 = (const float*)d_in[5];
  const float* W2 = (const float*)d_in[6];
  const float* W3 = (const float*)d_in[7];
  const float* W4 = (const float*)d_in[8];
  const float* Wv = (const float*)d_in[9];
  const float* Wout_w = (const float*)d_in[10];
  const float* Wout_b = (const float*)d_in[11];
  const float* res_w = (const float*)d_in[12];
  const float* res_b = (const float*)d_in[13];
  const float* ln_g = (const float*)d_in[14];
  const float* ln_b = (const float*)d_in[15];
  float* out = (float*)d_out;
  const int* src_idx = edge_index;
  const int* dst_idx = edge_index + NEDGE;

  float* base = (float*)d_ws;
  size_t off = 0;
  auto alloc = [&](size_t n) {
    float* p = base + off;
    off += (n + 63) & ~(size_t)63;
    return p;
  };
  float* A1T = alloc(1024);
  float* A2T = alloc(1024);
  float* a3 = alloc(8);
  float* attn_dst = alloc((size_t)N_DST * NH);
  float* attn_src = alloc((size_t)N_SRC * NH);
  float* V = alloc((size_t)N_SRC * D);
  float* R = alloc((size_t)N_DST * D);
  float* agg = alloc((size_t)N_DST * D);
  int* deg = (int*)alloc(N_DST);
  int* offs = (int*)alloc(N_DST + 1);
  int* pos = (int*)alloc(N_DST);
  int* bsum = (int*)alloc(64);
  float4* csr_pk = (float4*)alloc((size_t)NEDGE * 4);
  (void)ws_size; (void)in_sizes; (void)n_in; (void)out_size;

  const int NSB = (N_DST + 1023) / 1024;  // 49 scan blocks
  const int NBLK = (N_DST + BM - 1) / BM; // 782 gemm blocks per half

  hipMemsetAsync(deg, 0, N_DST * sizeof(int), stream);
  k_prep<<<2, 256, 0, stream>>>(W1, W2, W3, W4, A1T, A2T, a3);
  k_gemm_fused<<<2 * NBLK, 256, 0, stream>>>(
      src_feats, dst_feats, Wv, res_w, A2T, A1T, V, R, attn_src, attn_dst,
      N_DST, NBLK);
  k_hist<<<(NEDGE + 255) / 256, 256, 0, stream>>>(dst_idx, deg);
  k_scan1<<<NSB, 256, 0, stream>>>(deg, bsum);
  k_scan2<<<1, 64, 0, stream>>>(bsum, offs + N_DST, NSB);
  k_scan3<<<NSB, 256, 0, stream>>>(deg, bsum, offs, pos);
  k_scatter<<<(NEDGE + 255) / 256, 256, 0, stream>>>(src_idx, dst_idx, P_edge,
                                                     deter, pos, csr_pk);
  k_main<<<(N_DST + 31) / 32, 256, 0, stream>>>(offs, csr_pk, attn_src, attn_dst,
                                                a3, V, agg);
  k_out_fused<<<NBLK, 256, 0, stream>>>(agg, Wout_w, R, Wout_b, res_b, ln_g, ln_b,
                                        out, N_DST);
}